// Round 1
// 129.190 us; speedup vs baseline: 1.0451x; 1.0451x over previous
//
#include <hip/hip_runtime.h>

// Confusion-classification criterion (see reference):
//   pred = argmax(pred_logits[...,0:2])            (tie -> index 0)
//   cls  = g==1 ? (pred ? 1 : 2) : (pred ? 3 : 0)  (TP=1 FN=2 FP=3 TN=0)
//   loss = mean over B*N of -log_softmax(pred_confusion)[cls]
//
// R5 -> R6 theory: timed window includes a 256 MiB harness poison fill that
// leaves L2/L3 full of dirty lines; our read-allocates then force dirty
// evictions (writeback rides along with every input fetch), capping the part
// kernel at ~2.9 TB/s (~40 us for 117 MB vs ~18 us ideal).
// Fix: non-temporal (nt, non-allocating) loads for the three read-once input
// streams, so reads stop evicting dirty poison lines. Also K=4->8 with 2048
// blocks (same exact single pass, 24 VMEM in flight/wave for MLP).

typedef float f32x4 __attribute__((ext_vector_type(4)));
typedef float f32x2 __attribute__((ext_vector_type(2)));

#define NPART   2048
#define K_ELEMS 8

__device__ __forceinline__ float nll_one(f32x4 c, bool gpos, bool pred)
{
    // nll = logsumexp(c) - c[cls]
    float m   = fmaxf(fmaxf(c[0], c[1]), fmaxf(c[2], c[3]));
    float s   = __expf(c[0] - m) + __expf(c[1] - m) +
                __expf(c[2] - m) + __expf(c[3] - m);
    float lse = m + __logf(s);
    // cls: gpos&&pred->1, gpos&&!pred->2, !gpos&&pred->3, else 0
    float xc  = gpos ? (pred ? c[1] : c[2]) : (pred ? c[3] : c[0]);
    return lse - xc;
}

__global__ __launch_bounds__(256) void confusion_part_kernel(
    const f32x2* __restrict__ lg,    // [total] logit pairs
    const f32x4* __restrict__ conf,  // [total] confusion rows
    const int*   __restrict__ tg,    // [total] targets (int32)
    float* __restrict__ partials,    // [NPART]
    int total)
{
    const int tid   = threadIdx.x;
    const int chunk = 256 * K_ELEMS;             // 2048 elements per block-pass

    float acc = 0.0f;
    for (int base = blockIdx.x * chunk; base < total;
         base += gridDim.x * chunk) {

        if (base + chunk <= total) {
            // full tile: issue all coalesced non-allocating loads first
            f32x4 c[K_ELEMS];
            f32x2 l[K_ELEMS];
            int   g[K_ELEMS];
            #pragma unroll
            for (int k = 0; k < K_ELEMS; ++k) {
                int e = base + k * 256 + tid;    // unit stride per instruction
                c[k] = __builtin_nontemporal_load(conf + e);
                l[k] = __builtin_nontemporal_load(lg + e);
                g[k] = __builtin_nontemporal_load(tg + e);
            }
            #pragma unroll
            for (int k = 0; k < K_ELEMS; ++k)
                acc += nll_one(c[k], g[k] == 1, l[k][1] > l[k][0]);
        } else {
            // ragged tail tile (not hit at B*N = 4,194,304: 2048*2048 exact)
            for (int k = 0; k < K_ELEMS; ++k) {
                int e = base + k * 256 + tid;
                if (e < total) {
                    f32x2 l = __builtin_nontemporal_load(lg + e);
                    f32x4 c = __builtin_nontemporal_load(conf + e);
                    int   g = __builtin_nontemporal_load(tg + e);
                    acc += nll_one(c, g == 1, l[1] > l[0]);
                }
            }
        }
    }

    // wave-64 reduce
    #pragma unroll
    for (int off = 32; off > 0; off >>= 1)
        acc += __shfl_down(acc, off, 64);

    __shared__ float wsum[4];
    int lane = tid & 63;
    int wid  = tid >> 6;
    if (lane == 0) wsum[wid] = acc;
    __syncthreads();

    if (tid == 0)
        partials[blockIdx.x] = wsum[0] + wsum[1] + wsum[2] + wsum[3];
}

__global__ __launch_bounds__(256) void confusion_final_kernel(
    const f32x4* __restrict__ partials, float* __restrict__ out,
    int nquads, float inv_total)
{
    float acc = 0.0f;
    for (int i = threadIdx.x; i < nquads; i += 256) {
        f32x4 p = partials[i];
        acc += (p[0] + p[1]) + (p[2] + p[3]);
    }

    #pragma unroll
    for (int off = 32; off > 0; off >>= 1)
        acc += __shfl_down(acc, off, 64);

    __shared__ float wsum[4];
    int lane = threadIdx.x & 63;
    int wid  = threadIdx.x >> 6;
    if (lane == 0) wsum[wid] = acc;
    __syncthreads();

    if (threadIdx.x == 0)
        out[0] = (wsum[0] + wsum[1] + wsum[2] + wsum[3]) * inv_total;
}

extern "C" void kernel_launch(void* const* d_in, const int* in_sizes, int n_in,
                              void* d_out, int out_size, void* d_ws, size_t ws_size,
                              hipStream_t stream)
{
    const f32x2* lg    = (const f32x2*)d_in[0];
    const f32x4* conf  = (const f32x4*)d_in[1];
    const int*   tg    = (const int*)d_in[2];
    float*       out   = (float*)d_out;
    float*       parts = (float*)d_ws;        // NPART floats (8 KB)

    const int total = in_sizes[2];            // B*N = 4,194,304

    confusion_part_kernel<<<NPART, 256, 0, stream>>>(
        lg, conf, tg, parts, total);
    confusion_final_kernel<<<1, 256, 0, stream>>>(
        (const f32x4*)parts, out, NPART / 4, 1.0f / (float)total);
}